// Round 1
// baseline (515.135 us; speedup 1.0000x reference)
//
#include <hip/hip_runtime.h>

#define N_NODES 100000
#define N_EDGES 1600000
#define D 64
#define BN_EPS 1e-5f

// ---------------------------------------------------------------------------
// Kernel 1: scatter-mean accumulation. One wave (64 lanes) per edge iter:
// lane = feature. Coalesced 256B row reads of x[src], atomic adds to agg[dst].
// ---------------------------------------------------------------------------
__global__ __launch_bounds__(256) void scatter_kernel(
    const float* __restrict__ x,
    const int* __restrict__ ei,   // [2, E] flattened: src = ei[0:E), dst = ei[E:2E)
    float* __restrict__ agg,
    float* __restrict__ cnt) {
  const int lane = threadIdx.x & 63;
  const int wave = (blockIdx.x * blockDim.x + threadIdx.x) >> 6;
  const int nwaves = (gridDim.x * blockDim.x) >> 6;
  for (int e = wave; e < N_EDGES; e += nwaves) {
    int s = ei[e];            // wave-uniform -> scalar load
    int d = ei[N_EDGES + e];  // wave-uniform -> scalar load
    float v = x[s * D + lane];
    atomicAdd(&agg[d * D + lane], v);
    if (lane == 0) atomicAdd(&cnt[d], 1.0f);
  }
}

// ---------------------------------------------------------------------------
// Kernel 2: per-node transform. h = relu(mean_nb @ Wl^T + bl + x @ Wr^T).
// Weights staged transposed in LDS so lane j reads WlT[k*64+j] (stride-1 ->
// 2 lanes/bank, conflict-free). Broadcast of mean[k]/x[k] via v_readlane.
// 4 nodes per wave amortize the LDS weight reads 4x. Also accumulates
// per-feature sum / sum-of-squares for BatchNorm batch stats.
// h is written to d_out (used as scratch; finalize updates it in place).
// ---------------------------------------------------------------------------
__global__ __launch_bounds__(256) void transform_kernel(
    const float* __restrict__ x,
    const float* __restrict__ agg,
    const float* __restrict__ cnt,
    const float* __restrict__ Wl,
    const float* __restrict__ bl,
    const float* __restrict__ Wr,
    float* __restrict__ hout,    // = d_out, holds pre-BN h
    float* __restrict__ sums) {  // [0:64) sum, [64:128) sumsq
  __shared__ float WlT[D * D];
  __shared__ float WrT[D * D];
  __shared__ float bsum[D];
  __shared__ float bsq[D];
  for (int i = threadIdx.x; i < D * D; i += blockDim.x) {
    int j = i >> 6, k = i & 63;
    WlT[k * D + j] = Wl[i];
    WrT[k * D + j] = Wr[i];
  }
  if (threadIdx.x < D) { bsum[threadIdx.x] = 0.f; bsq[threadIdx.x] = 0.f; }
  __syncthreads();

  const int lane = threadIdx.x & 63;
  const int wid = (blockIdx.x * blockDim.x + threadIdx.x) >> 6;
  const int nwaves = (gridDim.x * blockDim.x) >> 6;
  const float bias = bl[lane];
  float psum = 0.f, psq = 0.f;

  // N_NODES == 100000 is divisible by 4, so every 4-node group is full.
  for (int n0 = wid * 4; n0 < N_NODES; n0 += nwaves * 4) {
    float mean[4], xv[4], acc[4];
#pragma unroll
    for (int t = 0; t < 4; ++t) {
      int n = n0 + t;
      float c = cnt[n];                          // wave-uniform scalar load
      float inv = 1.0f / fmaxf(c, 1.0f);
      mean[t] = agg[n * D + lane] * inv;
      xv[t] = x[n * D + lane];
      acc[t] = bias;
    }
#pragma unroll
    for (int k = 0; k < D; ++k) {
      float wl = WlT[k * D + lane];
      float wr = WrT[k * D + lane];
#pragma unroll
      for (int t = 0; t < 4; ++t) {
        float mk = __int_as_float(__builtin_amdgcn_readlane(__float_as_int(mean[t]), k));
        float xk = __int_as_float(__builtin_amdgcn_readlane(__float_as_int(xv[t]), k));
        acc[t] += mk * wl + xk * wr;
      }
    }
#pragma unroll
    for (int t = 0; t < 4; ++t) {
      float hv = fmaxf(acc[t], 0.f);
      hout[(n0 + t) * D + lane] = hv;
      psum += hv;
      psq += hv * hv;
    }
  }

  atomicAdd(&bsum[lane], psum);  // LDS atomic across the block's 4 waves
  atomicAdd(&bsq[lane], psq);
  __syncthreads();
  if (threadIdx.x < D) {
    atomicAdd(&sums[threadIdx.x], bsum[threadIdx.x]);
    atomicAdd(&sums[D + threadIdx.x], bsq[threadIdx.x]);
  }
}

// ---------------------------------------------------------------------------
// Kernel 3: finalize BN stats -> per-feature scale & shift.
// ---------------------------------------------------------------------------
__global__ void stats_kernel(const float* __restrict__ sums,
                             const float* __restrict__ gamma,
                             const float* __restrict__ beta,
                             float* __restrict__ ss) {
  int d = threadIdx.x;
  if (d >= D) return;
  float mu = sums[d] / (float)N_NODES;
  float var = sums[D + d] / (float)N_NODES - mu * mu;
  float inv = rsqrtf(fmaxf(var, 0.f) + BN_EPS);
  float sc = gamma[d] * inv;
  ss[d] = sc;
  ss[D + d] = beta[d] - mu * sc;
}

// ---------------------------------------------------------------------------
// Kernel 4: out = x + h*scale + shift (h currently stored in d_out; in-place).
// ---------------------------------------------------------------------------
__global__ __launch_bounds__(256) void finalize_kernel(
    const float* __restrict__ x,
    const float* __restrict__ ss,
    float* __restrict__ out) {
  const int total = N_NODES * D / 4;
  int i = blockIdx.x * blockDim.x + threadIdx.x;  // float4 index
  if (i >= total) return;
  int q = i & 15;  // which float4 of the 64-wide feature row
  float4 sc = ((const float4*)ss)[q];
  float4 sh = ((const float4*)ss)[16 + q];
  float4 hv = ((const float4*)out)[i];
  float4 xv = ((const float4*)x)[i];
  float4 r;
  r.x = xv.x + hv.x * sc.x + sh.x;
  r.y = xv.y + hv.y * sc.y + sh.y;
  r.z = xv.z + hv.z * sc.z + sh.z;
  r.w = xv.w + hv.w * sc.w + sh.w;
  ((float4*)out)[i] = r;
}

extern "C" void kernel_launch(void* const* d_in, const int* in_sizes, int n_in,
                              void* d_out, int out_size, void* d_ws, size_t ws_size,
                              hipStream_t stream) {
  const float* x     = (const float*)d_in[0];
  const int*   ei    = (const int*)d_in[1];
  const float* Wl    = (const float*)d_in[2];
  const float* bl    = (const float*)d_in[3];
  const float* Wr    = (const float*)d_in[4];
  const float* gamma = (const float*)d_in[5];
  const float* beta  = (const float*)d_in[6];
  float* out = (float*)d_out;

  // workspace layout (floats)
  float* agg  = (float*)d_ws;                 // N*D
  float* cnt  = agg + (size_t)N_NODES * D;    // N
  float* sums = cnt + N_NODES;                // 128 (sum, sumsq)
  float* ss   = sums + 2 * D;                 // 128 (scale, shift)

  // zero the accumulators every call (harness does not re-poison between replays)
  size_t zero_bytes = ((size_t)N_NODES * D + N_NODES + 2 * D) * sizeof(float);
  hipMemsetAsync(d_ws, 0, zero_bytes, stream);

  scatter_kernel<<<2048, 256, 0, stream>>>(x, ei, agg, cnt);
  transform_kernel<<<1024, 256, 0, stream>>>(x, agg, cnt, Wl, bl, Wr, out, sums);
  stats_kernel<<<1, 64, 0, stream>>>(sums, gamma, beta, ss);
  finalize_kernel<<<(N_NODES * D / 4 + 255) / 256, 256, 0, stream>>>(x, ss, out);
}

// Round 2
// 363.676 us; speedup vs baseline: 1.4165x; 1.4165x over previous
//
#include <hip/hip_runtime.h>

#define N_NODES 100000
#define N_EDGES 1600000
#define D 64
#define BN_EPS 1e-5f
#define SCAN_BLK 256
#define NBLK ((N_NODES + SCAN_BLK - 1) / SCAN_BLK)  // 391

// ---------------------------------------------------------------------------
// CSR build step 1: per-destination degree histogram (int atomics, 400KB
// counter footprint -> L2-resident, cheap).
// ---------------------------------------------------------------------------
__global__ __launch_bounds__(256) void degree_kernel(
    const int* __restrict__ ei, int* __restrict__ deg) {
  int e = blockIdx.x * blockDim.x + threadIdx.x;
  if (e < N_EDGES) atomicAdd(&deg[ei[N_EDGES + e]], 1);
}

// ---------------------------------------------------------------------------
// CSR build step 2a/2b/2c: exclusive prefix scan of deg[N] -> offset[N].
// ---------------------------------------------------------------------------
__global__ __launch_bounds__(SCAN_BLK) void scan1_kernel(
    const int* __restrict__ deg, int* __restrict__ partial) {
  __shared__ int s[SCAN_BLK];
  int idx = blockIdx.x * SCAN_BLK + threadIdx.x;
  s[threadIdx.x] = (idx < N_NODES) ? deg[idx] : 0;
  __syncthreads();
  for (int off = SCAN_BLK / 2; off > 0; off >>= 1) {
    if (threadIdx.x < off) s[threadIdx.x] += s[threadIdx.x + off];
    __syncthreads();
  }
  if (threadIdx.x == 0) partial[blockIdx.x] = s[0];
}

__global__ __launch_bounds__(512) void scan2_kernel(
    const int* __restrict__ partial, int* __restrict__ blockpref) {
  __shared__ int s[512];
  int tid = threadIdx.x;
  int v = (tid < NBLK) ? partial[tid] : 0;
  s[tid] = v;
  __syncthreads();
  for (int off = 1; off < 512; off <<= 1) {
    int t = (tid >= off) ? s[tid - off] : 0;
    __syncthreads();
    s[tid] += t;
    __syncthreads();
  }
  if (tid < NBLK) blockpref[tid] = s[tid] - v;  // exclusive
}

__global__ __launch_bounds__(SCAN_BLK) void scan3_kernel(
    const int* __restrict__ deg, const int* __restrict__ blockpref,
    int* __restrict__ offset) {
  __shared__ int s[SCAN_BLK];
  int tid = threadIdx.x;
  int idx = blockIdx.x * SCAN_BLK + tid;
  int v = (idx < N_NODES) ? deg[idx] : 0;
  s[tid] = v;
  __syncthreads();
  for (int off = 1; off < SCAN_BLK; off <<= 1) {
    int t = (tid >= off) ? s[tid - off] : 0;
    __syncthreads();
    s[tid] += t;
    __syncthreads();
  }
  if (idx < N_NODES) offset[idx] = blockpref[blockIdx.x] + s[tid] - v;
}

// ---------------------------------------------------------------------------
// CSR build step 3: scatter edge sources into dst-grouped order.
// ---------------------------------------------------------------------------
__global__ __launch_bounds__(256) void fill_kernel(
    const int* __restrict__ ei, const int* __restrict__ offset,
    int* __restrict__ cursor, int* __restrict__ sorted_src) {
  int e = blockIdx.x * blockDim.x + threadIdx.x;
  if (e >= N_EDGES) return;
  int d = ei[N_EDGES + e];
  int p = offset[d] + atomicAdd(&cursor[d], 1);
  sorted_src[p] = ei[e];
}

// ---------------------------------------------------------------------------
// Fused gather-mean + SAGE transform + ReLU + BN partial stats.
// One wave per destination node; lane = feature. Neighbor ids loaded 64 at a
// time into a register (coalesced), broadcast via v_readlane; each neighbor
// row is a coalesced 256B read from L2/LLC-resident x. Then the dual 64x64
// matmul with LDS-transposed weights and readlane broadcasts of mean/x.
// ---------------------------------------------------------------------------
__global__ __launch_bounds__(256) void gather_transform_kernel(
    const float* __restrict__ x,
    const int* __restrict__ sorted_src,
    const int* __restrict__ offset,
    const int* __restrict__ deg,
    const float* __restrict__ Wl,
    const float* __restrict__ bl,
    const float* __restrict__ Wr,
    float* __restrict__ hout,    // = d_out, holds pre-BN h
    float* __restrict__ sums) {  // [0:64) sum, [64:128) sumsq
  __shared__ float WlT[D * D];
  __shared__ float WrT[D * D];
  __shared__ float bsum[D];
  __shared__ float bsq[D];
  for (int i = threadIdx.x; i < D * D; i += blockDim.x) {
    int j = i >> 6, k = i & 63;
    WlT[k * D + j] = Wl[i];
    WrT[k * D + j] = Wr[i];
  }
  if (threadIdx.x < D) { bsum[threadIdx.x] = 0.f; bsq[threadIdx.x] = 0.f; }
  __syncthreads();

  const int lane = threadIdx.x & 63;
  const int wid = (blockIdx.x * blockDim.x + threadIdx.x) >> 6;
  const int nwaves = (gridDim.x * blockDim.x) >> 6;
  const float bias = bl[lane];
  float psum = 0.f, psq = 0.f;

  for (int n = wid; n < N_NODES; n += nwaves) {
    int dg = __builtin_amdgcn_readfirstlane(deg[n]);
    int off = __builtin_amdgcn_readfirstlane(offset[n]);

    float s0 = 0.f, s1 = 0.f, s2 = 0.f, s3 = 0.f;
    for (int base = 0; base < dg; base += 64) {
      int rem = dg - base;
      int m = rem < 64 ? rem : 64;
      int id = (lane < m) ? sorted_src[off + base + lane] : 0;
      int j = 0;
      for (; j + 4 <= m; j += 4) {
        int a0 = __builtin_amdgcn_readlane(id, j);
        int a1 = __builtin_amdgcn_readlane(id, j + 1);
        int a2 = __builtin_amdgcn_readlane(id, j + 2);
        int a3 = __builtin_amdgcn_readlane(id, j + 3);
        s0 += x[a0 * D + lane];
        s1 += x[a1 * D + lane];
        s2 += x[a2 * D + lane];
        s3 += x[a3 * D + lane];
      }
      for (; j < m; ++j) {
        int a = __builtin_amdgcn_readlane(id, j);
        s0 += x[a * D + lane];
      }
    }
    float inv = 1.0f / fmaxf((float)dg, 1.0f);
    float mean = ((s0 + s1) + (s2 + s3)) * inv;
    float xv = x[n * D + lane];

    float acc = bias;
#pragma unroll
    for (int k = 0; k < D; ++k) {
      float wl = WlT[k * D + lane];
      float wr = WrT[k * D + lane];
      float mk = __int_as_float(__builtin_amdgcn_readlane(__float_as_int(mean), k));
      float xk = __int_as_float(__builtin_amdgcn_readlane(__float_as_int(xv), k));
      acc += mk * wl + xk * wr;
    }
    float hv = fmaxf(acc, 0.f);
    hout[n * D + lane] = hv;
    psum += hv;
    psq += hv * hv;
  }

  atomicAdd(&bsum[lane], psum);
  atomicAdd(&bsq[lane], psq);
  __syncthreads();
  if (threadIdx.x < D) {
    atomicAdd(&sums[threadIdx.x], bsum[threadIdx.x]);
    atomicAdd(&sums[D + threadIdx.x], bsq[threadIdx.x]);
  }
}

// ---------------------------------------------------------------------------
// BN stats -> per-feature scale & shift.
// ---------------------------------------------------------------------------
__global__ void stats_kernel(const float* __restrict__ sums,
                             const float* __restrict__ gamma,
                             const float* __restrict__ beta,
                             float* __restrict__ ss) {
  int d = threadIdx.x;
  if (d >= D) return;
  float mu = sums[d] / (float)N_NODES;
  float var = sums[D + d] / (float)N_NODES - mu * mu;
  float inv = rsqrtf(fmaxf(var, 0.f) + BN_EPS);
  float sc = gamma[d] * inv;
  ss[d] = sc;
  ss[D + d] = beta[d] - mu * sc;
}

// ---------------------------------------------------------------------------
// out = x + h*scale + shift (h is in d_out; update in place).
// ---------------------------------------------------------------------------
__global__ __launch_bounds__(256) void finalize_kernel(
    const float* __restrict__ x,
    const float* __restrict__ ss,
    float* __restrict__ out) {
  const int total = N_NODES * D / 4;
  int i = blockIdx.x * blockDim.x + threadIdx.x;  // float4 index
  if (i >= total) return;
  int q = i & 15;
  float4 sc = ((const float4*)ss)[q];
  float4 sh = ((const float4*)ss)[16 + q];
  float4 hv = ((const float4*)out)[i];
  float4 xv = ((const float4*)x)[i];
  float4 r;
  r.x = xv.x + hv.x * sc.x + sh.x;
  r.y = xv.y + hv.y * sc.y + sh.y;
  r.z = xv.z + hv.z * sc.z + sh.z;
  r.w = xv.w + hv.w * sc.w + sh.w;
  ((float4*)out)[i] = r;
}

extern "C" void kernel_launch(void* const* d_in, const int* in_sizes, int n_in,
                              void* d_out, int out_size, void* d_ws, size_t ws_size,
                              hipStream_t stream) {
  const float* x     = (const float*)d_in[0];
  const int*   ei    = (const int*)d_in[1];
  const float* Wl    = (const float*)d_in[2];
  const float* bl    = (const float*)d_in[3];
  const float* Wr    = (const float*)d_in[4];
  const float* gamma = (const float*)d_in[5];
  const float* beta  = (const float*)d_in[6];
  float* out = (float*)d_out;

  // workspace layout (ints/floats, 4B each). Zeroed region first.
  int* deg        = (int*)d_ws;                        // N   (zeroed)
  int* cursor     = deg + N_NODES;                     // N   (zeroed)
  float* sums     = (float*)(cursor + N_NODES);        // 128 (zeroed)
  int* sorted_src = (int*)(sums + 2 * D);              // E
  int* offset     = sorted_src + N_EDGES;              // N
  int* partial    = offset + N_NODES;                  // NBLK
  int* blockpref  = partial + NBLK;                    // NBLK
  float* ss       = (float*)(blockpref + NBLK);        // 128

  size_t zero_bytes = (size_t)(2 * N_NODES + 2 * D) * sizeof(int);
  hipMemsetAsync(d_ws, 0, zero_bytes, stream);

  const int eblocks = (N_EDGES + 255) / 256;
  degree_kernel<<<eblocks, 256, 0, stream>>>(ei, deg);
  scan1_kernel<<<NBLK, SCAN_BLK, 0, stream>>>(deg, partial);
  scan2_kernel<<<1, 512, 0, stream>>>(partial, blockpref);
  scan3_kernel<<<NBLK, SCAN_BLK, 0, stream>>>(deg, blockpref, offset);
  fill_kernel<<<eblocks, 256, 0, stream>>>(ei, offset, cursor, sorted_src);
  gather_transform_kernel<<<2048, 256, 0, stream>>>(
      x, sorted_src, offset, deg, Wl, bl, Wr, out, sums);
  stats_kernel<<<1, 64, 0, stream>>>(sums, gamma, beta, ss);
  finalize_kernel<<<(N_NODES * D / 4 + 255) / 256, 256, 0, stream>>>(x, ss, out);
}

// Round 3
// 320.272 us; speedup vs baseline: 1.6084x; 1.1355x over previous
//
#include <hip/hip_runtime.h>

#define N_NODES 100000
#define N_EDGES 1600000
#define D 64
#define BN_EPS 1e-5f
#define SCAN_BLK 256
#define NBLK ((N_NODES + SCAN_BLK - 1) / SCAN_BLK)  // 391
#define TILES (N_NODES / 16)                        // 6250

typedef __attribute__((ext_vector_type(8))) short short8;
typedef __attribute__((ext_vector_type(4))) float f32x4;
typedef unsigned int uint;

__device__ inline unsigned short f2bf(float f) {  // RNE fp32 -> bf16
  uint u = __float_as_uint(f);
  uint r = (u + 0x7fffu + ((u >> 16) & 1u)) >> 16;
  return (unsigned short)r;
}

// ---------------------------------------------------------------------------
// x -> bf16 (packed pairs) + degree histogram, fused.
// ---------------------------------------------------------------------------
__global__ __launch_bounds__(256) void convert_degree_kernel(
    const float* __restrict__ x, const int* __restrict__ ei,
    int* __restrict__ deg, uint4* __restrict__ xb4) {
  int i = blockIdx.x * 256 + threadIdx.x;
  if (i < N_NODES * D / 8) {
    const float4* xf = (const float4*)x;
    float4 v0 = xf[i * 2], v1 = xf[i * 2 + 1];
    uint4 o;
    o.x = ((uint)f2bf(v0.y) << 16) | f2bf(v0.x);
    o.y = ((uint)f2bf(v0.w) << 16) | f2bf(v0.z);
    o.z = ((uint)f2bf(v1.y) << 16) | f2bf(v1.x);
    o.w = ((uint)f2bf(v1.w) << 16) | f2bf(v1.z);
    xb4[i] = o;
  }
  if (i < N_EDGES) atomicAdd(&deg[ei[N_EDGES + i]], 1);
}

// ---------------------------------------------------------------------------
// exclusive prefix scan of deg[N] -> offset[N]  (3 launches)
// ---------------------------------------------------------------------------
__global__ __launch_bounds__(SCAN_BLK) void scan1_kernel(
    const int* __restrict__ deg, int* __restrict__ partial) {
  __shared__ int s[SCAN_BLK];
  int idx = blockIdx.x * SCAN_BLK + threadIdx.x;
  s[threadIdx.x] = (idx < N_NODES) ? deg[idx] : 0;
  __syncthreads();
  for (int off = SCAN_BLK / 2; off > 0; off >>= 1) {
    if (threadIdx.x < off) s[threadIdx.x] += s[threadIdx.x + off];
    __syncthreads();
  }
  if (threadIdx.x == 0) partial[blockIdx.x] = s[0];
}

__global__ __launch_bounds__(512) void scan2_kernel(
    const int* __restrict__ partial, int* __restrict__ blockpref) {
  __shared__ int s[512];
  int tid = threadIdx.x;
  int v = (tid < NBLK) ? partial[tid] : 0;
  s[tid] = v;
  __syncthreads();
  for (int off = 1; off < 512; off <<= 1) {
    int t = (tid >= off) ? s[tid - off] : 0;
    __syncthreads();
    s[tid] += t;
    __syncthreads();
  }
  if (tid < NBLK) blockpref[tid] = s[tid] - v;  // exclusive
}

__global__ __launch_bounds__(SCAN_BLK) void scan3_kernel(
    const int* __restrict__ deg, const int* __restrict__ blockpref,
    int* __restrict__ offset) {
  __shared__ int s[SCAN_BLK];
  int tid = threadIdx.x;
  int idx = blockIdx.x * SCAN_BLK + tid;
  int v = (idx < N_NODES) ? deg[idx] : 0;
  s[tid] = v;
  __syncthreads();
  for (int off = 1; off < SCAN_BLK; off <<= 1) {
    int t = (tid >= off) ? s[tid - off] : 0;
    __syncthreads();
    s[tid] += t;
    __syncthreads();
  }
  if (idx < N_NODES) offset[idx] = blockpref[blockIdx.x] + s[tid] - v;
}

// ---------------------------------------------------------------------------
// scatter edge sources into dst-grouped order
// ---------------------------------------------------------------------------
__global__ __launch_bounds__(256) void fill_kernel(
    const int* __restrict__ ei, const int* __restrict__ offset,
    int* __restrict__ cursor, int* __restrict__ sorted_src) {
  int e = blockIdx.x * blockDim.x + threadIdx.x;
  if (e >= N_EDGES) return;
  int d = ei[N_EDGES + e];
  int p = offset[d] + atomicAdd(&cursor[d], 1);
  sorted_src[p] = ei[e];
}

// ---------------------------------------------------------------------------
// Fused: gather-mean (bf16, 2 neighbor rows per dword load) -> LDS ->
// MFMA 16x16x32_bf16 transform (wave w owns output col-tile w) -> ReLU ->
// h to d_out + BN partial sums.
// Per 16-node tile: 4 waves each gather 4 nodes into padded LDS rows
// (144B stride: 16B frag reads land on distinct banks), then each wave
// does 4 MFMAs (meanb@WlT + xb@WrT over K=64).
// ---------------------------------------------------------------------------
__global__ __launch_bounds__(256) void gather_mfma_kernel(
    const uint* __restrict__ xb,        // [N][32] packed bf16 pairs
    const int* __restrict__ sorted_src,
    const int* __restrict__ offset,
    const int* __restrict__ deg,
    const float* __restrict__ Wl,
    const float* __restrict__ bl,
    const float* __restrict__ Wr,
    float* __restrict__ hout,           // = d_out, pre-BN h
    float* __restrict__ sums) {         // [0:64) sum, [64:128) sumsq
  __shared__ short8 bfrag[2][4][2][64];         // [mat][ct][kk][lane] 16KB
  __shared__ __align__(16) uint smean[16 * 36]; // 16 rows x 144B (pad +16B)
  __shared__ float bsum[D], bsq[D];

  const int tid = threadIdx.x;
  const int lane = tid & 63;
  const int w = tid >> 6;  // wave id == output col-tile ct

  // Prepack weight B-fragments: B[k][col] = W[col][k], lane l holds
  // k = kk*32 + (l>>4)*8 + i, col = ct*16 + (l&15).
  for (int e = tid; e < 1024; e += 256) {
    int mat = e >> 9, r = e & 511;
    int ct = r >> 7, kk = (r >> 6) & 1, l = r & 63;
    int col = ct * 16 + (l & 15);
    int k0 = kk * 32 + (l >> 4) * 8;
    const float* W = mat ? Wr : Wl;
    short8 sv;
#pragma unroll
    for (int i = 0; i < 8; ++i) sv[i] = (short)f2bf(W[col * 64 + k0 + i]);
    bfrag[mat][ct][kk][l] = sv;
  }
  __syncthreads();

  short8 bWl0 = bfrag[0][w][0][lane], bWl1 = bfrag[0][w][1][lane];
  short8 bWr0 = bfrag[1][w][0][lane], bWr1 = bfrag[1][w][1][lane];
  const float bias = bl[w * 16 + (lane & 15)];
  float psum = 0.f, psq = 0.f;
  const int q = lane & 31;

  for (int t = blockIdx.x; t < TILES; t += (int)gridDim.x) {
    const int n0 = t * 16;
    // ---- phase 1: each wave gathers 4 node means into smean ----
#pragma unroll
    for (int s = 0; s < 4; ++s) {
      int n = n0 + w * 4 + s;
      int dg = __builtin_amdgcn_readfirstlane(deg[n]);
      int off = __builtin_amdgcn_readfirstlane(offset[n]);
      float a0 = 0.f, a1 = 0.f, c0 = 0.f, c1 = 0.f;
      for (int base = 0; base < dg; base += 64) {
        int rem = dg - base;
        int m = rem < 64 ? rem : 64;
        int id = (lane < m) ? sorted_src[off + base + lane] : 0;
        int j = 0;
        for (; j + 4 <= m; j += 4) {
          int i0 = __builtin_amdgcn_readlane(id, j);
          int i1 = __builtin_amdgcn_readlane(id, j + 1);
          int i2 = __builtin_amdgcn_readlane(id, j + 2);
          int i3 = __builtin_amdgcn_readlane(id, j + 3);
          uint r0 = xb[(uint)(lane < 32 ? i0 : i1) * 32u + q];
          uint r1 = xb[(uint)(lane < 32 ? i2 : i3) * 32u + q];
          a0 += __uint_as_float(r0 << 16);
          a1 += __uint_as_float(r0 & 0xffff0000u);
          c0 += __uint_as_float(r1 << 16);
          c1 += __uint_as_float(r1 & 0xffff0000u);
        }
        if (j + 2 <= m) {
          int i0 = __builtin_amdgcn_readlane(id, j);
          int i1 = __builtin_amdgcn_readlane(id, j + 1);
          uint r0 = xb[(uint)(lane < 32 ? i0 : i1) * 32u + q];
          a0 += __uint_as_float(r0 << 16);
          a1 += __uint_as_float(r0 & 0xffff0000u);
          j += 2;
        }
        if (j < m) {
          int i0 = __builtin_amdgcn_readlane(id, j);
          uint r0 = xb[(uint)i0 * 32u + q];
          a0 += (lane < 32) ? __uint_as_float(r0 << 16) : 0.f;
          a1 += (lane < 32) ? __uint_as_float(r0 & 0xffff0000u) : 0.f;
        }
      }
      float t0 = a0 + c0, t1 = a1 + c1;
      t0 += __shfl_xor(t0, 32, 64);
      t1 += __shfl_xor(t1, 32, 64);
      float inv = 1.0f / fmaxf((float)dg, 1.0f);
      uint p = ((uint)f2bf(t1 * inv) << 16) | (uint)f2bf(t0 * inv);
      if (lane < 32) smean[(w * 4 + s) * 36 + q] = p;
    }
    __syncthreads();

    // ---- phase 2: MFMA, wave w -> output cols [w*16, w*16+16) ----
    {
      const int r16 = lane & 15;   // A row / C col-within-tile
      const int kg = lane >> 4;    // k-group
      short8 am0 = *(const short8*)&smean[r16 * 36 + kg * 4];
      short8 am1 = *(const short8*)&smean[r16 * 36 + 16 + kg * 4];
      const short8* xbf = (const short8*)xb;  // 16B units, 8 per row
      short8 ax0 = xbf[(size_t)(n0 + r16) * 8 + kg];
      short8 ax1 = xbf[(size_t)(n0 + r16) * 8 + 4 + kg];
      f32x4 acc = {0.f, 0.f, 0.f, 0.f};
      acc = __builtin_amdgcn_mfma_f32_16x16x32_bf16(am0, bWl0, acc, 0, 0, 0);
      acc = __builtin_amdgcn_mfma_f32_16x16x32_bf16(am1, bWl1, acc, 0, 0, 0);
      acc = __builtin_amdgcn_mfma_f32_16x16x32_bf16(ax0, bWr0, acc, 0, 0, 0);
      acc = __builtin_amdgcn_mfma_f32_16x16x32_bf16(ax1, bWr1, acc, 0, 0, 0);
#pragma unroll
      for (int r = 0; r < 4; ++r) {
        float hv = fmaxf(acc[r] + bias, 0.f);
        hout[(size_t)(n0 + kg * 4 + r) * D + w * 16 + r16] = hv;
        psum += hv;
        psq += hv * hv;
      }
    }
    __syncthreads();  // smean reuse protection
  }

  // BN partial sums: lane holds feature w*16+(lane&15); reduce k-groups.
  psum += __shfl_xor(psum, 16, 64);
  psum += __shfl_xor(psum, 32, 64);
  psq += __shfl_xor(psq, 16, 64);
  psq += __shfl_xor(psq, 32, 64);
  if (lane < 16) {  // unique (w,lane) -> plain store
    bsum[w * 16 + lane] = psum;
    bsq[w * 16 + lane] = psq;
  }
  __syncthreads();
  if (tid < D) {
    atomicAdd(&sums[tid], bsum[tid]);
    atomicAdd(&sums[D + tid], bsq[tid]);
  }
}

// ---------------------------------------------------------------------------
// BN stats -> per-feature scale & shift.
// ---------------------------------------------------------------------------
__global__ void stats_kernel(const float* __restrict__ sums,
                             const float* __restrict__ gamma,
                             const float* __restrict__ beta,
                             float* __restrict__ ss) {
  int d = threadIdx.x;
  if (d >= D) return;
  float mu = sums[d] / (float)N_NODES;
  float var = sums[D + d] / (float)N_NODES - mu * mu;
  float inv = rsqrtf(fmaxf(var, 0.f) + BN_EPS);
  float sc = gamma[d] * inv;
  ss[d] = sc;
  ss[D + d] = beta[d] - mu * sc;
}

// ---------------------------------------------------------------------------
// out = x + h*scale + shift (h in d_out; in-place).
// ---------------------------------------------------------------------------
__global__ __launch_bounds__(256) void finalize_kernel(
    const float* __restrict__ x,
    const float* __restrict__ ss,
    float* __restrict__ out) {
  const int total = N_NODES * D / 4;
  int i = blockIdx.x * blockDim.x + threadIdx.x;
  if (i >= total) return;
  int qq = i & 15;
  float4 sc = ((const float4*)ss)[qq];
  float4 sh = ((const float4*)ss)[16 + qq];
  float4 hv = ((const float4*)out)[i];
  float4 xv = ((const float4*)x)[i];
  float4 r;
  r.x = xv.x + hv.x * sc.x + sh.x;
  r.y = xv.y + hv.y * sc.y + sh.y;
  r.z = xv.z + hv.z * sc.z + sh.z;
  r.w = xv.w + hv.w * sc.w + sh.w;
  ((float4*)out)[i] = r;
}

extern "C" void kernel_launch(void* const* d_in, const int* in_sizes, int n_in,
                              void* d_out, int out_size, void* d_ws, size_t ws_size,
                              hipStream_t stream) {
  const float* x     = (const float*)d_in[0];
  const int*   ei    = (const int*)d_in[1];
  const float* Wl    = (const float*)d_in[2];
  const float* bl    = (const float*)d_in[3];
  const float* Wr    = (const float*)d_in[4];
  const float* gamma = (const float*)d_in[5];
  const float* beta  = (const float*)d_in[6];
  float* out = (float*)d_out;

  // workspace layout (4B units); zeroed region first
  int* deg        = (int*)d_ws;                    // N   (zeroed)
  int* cursor     = deg + N_NODES;                 // N   (zeroed)
  float* sums     = (float*)(cursor + N_NODES);    // 128 (zeroed)
  int* sorted_src = (int*)(sums + 2 * D);          // E
  int* offset     = sorted_src + N_EDGES;          // N
  int* partial    = offset + N_NODES;              // NBLK
  int* blockpref  = partial + NBLK;                // NBLK
  float* ss       = (float*)(blockpref + NBLK);    // 128
  uint* xb        = (uint*)(ss + 2 * D);           // N*32 (bf16-pair rows)

  size_t zero_bytes = (size_t)(2 * N_NODES + 2 * D) * sizeof(int);
  hipMemsetAsync(d_ws, 0, zero_bytes, stream);

  const int eblocks = (N_EDGES + 255) / 256;
  convert_degree_kernel<<<eblocks, 256, 0, stream>>>(x, ei, deg, (uint4*)xb);
  scan1_kernel<<<NBLK, SCAN_BLK, 0, stream>>>(deg, partial);
  scan2_kernel<<<1, 512, 0, stream>>>(partial, blockpref);
  scan3_kernel<<<NBLK, SCAN_BLK, 0, stream>>>(deg, blockpref, offset);
  fill_kernel<<<eblocks, 256, 0, stream>>>(ei, offset, cursor, sorted_src);
  gather_mfma_kernel<<<2048, 256, 0, stream>>>(
      xb, sorted_src, offset, deg, Wl, bl, Wr, out, sums);
  stats_kernel<<<1, 64, 0, stream>>>(sums, gamma, beta, ss);
  finalize_kernel<<<(N_NODES * D / 4 + 255) / 256, 256, 0, stream>>>(x, ss, out);
}

// Round 4
// 274.913 us; speedup vs baseline: 1.8738x; 1.1650x over previous
//
#include <hip/hip_runtime.h>

#define N_NODES 100000
#define N_EDGES 1600000
#define D 64
#define BN_EPS 1e-5f
#define SB 512
#define NSB ((N_NODES + SB - 1) / SB)   // 196
#define TILES (N_NODES / 16)            // 6250
#define GT_BLOCKS ((TILES + 7) / 8)     // 782 (8 waves/block, 1 tile/wave)

typedef __attribute__((ext_vector_type(8))) short short8;
typedef __attribute__((ext_vector_type(4))) float f32x4;
typedef unsigned int uint;

__device__ inline unsigned short f2bf(float f) {  // RNE fp32 -> bf16
  uint u = __float_as_uint(f);
  uint r = (u + 0x7fffu + ((u >> 16) & 1u)) >> 16;
  return (unsigned short)r;
}

// ---------------------------------------------------------------------------
// x -> bf16 packed rows + zero dummy row (id N_NODES) + degree histogram.
// ---------------------------------------------------------------------------
__global__ __launch_bounds__(256) void convert_degree_kernel(
    const float* __restrict__ x, const int* __restrict__ ei,
    int* __restrict__ deg, uint4* __restrict__ xb4) {
  int i = blockIdx.x * 256 + threadIdx.x;
  if (i < N_NODES * D / 8) {
    const float4* xf = (const float4*)x;
    float4 v0 = xf[i * 2], v1 = xf[i * 2 + 1];
    uint4 o;
    o.x = ((uint)f2bf(v0.y) << 16) | f2bf(v0.x);
    o.y = ((uint)f2bf(v0.w) << 16) | f2bf(v0.z);
    o.z = ((uint)f2bf(v1.y) << 16) | f2bf(v1.x);
    o.w = ((uint)f2bf(v1.w) << 16) | f2bf(v1.z);
    xb4[i] = o;
  }
  if (i < 8) xb4[(size_t)N_NODES * 8 + i] = make_uint4(0, 0, 0, 0);
  if (i < N_EDGES) atomicAdd(&deg[ei[N_EDGES + i]], 1);
}

// ---------------------------------------------------------------------------
// scan step 1: per-block sums of padded degree (deg rounded up to x4).
// ---------------------------------------------------------------------------
__global__ __launch_bounds__(SB) void scan1_kernel(
    const int* __restrict__ deg, int* __restrict__ partial) {
  __shared__ int s[SB];
  int idx = blockIdx.x * SB + threadIdx.x;
  int v = (idx < N_NODES) ? ((deg[idx] + 3) & ~3) : 0;
  s[threadIdx.x] = v;
  __syncthreads();
  for (int off = SB / 2; off > 0; off >>= 1) {
    if (threadIdx.x < off) s[threadIdx.x] += s[threadIdx.x + off];
    __syncthreads();
  }
  if (threadIdx.x == 0) partial[blockIdx.x] = s[0];
}

// ---------------------------------------------------------------------------
// scan step 2 (fused): each block scans the 196 partials in LDS, then does
// its local exclusive scan of padded degrees -> offset[]. Also pre-fills the
// <=3 padding slots of each node's segment with the dummy id N_NODES.
// ---------------------------------------------------------------------------
__global__ __launch_bounds__(SB) void scan2_kernel(
    const int* __restrict__ deg, const int* __restrict__ partial,
    int* __restrict__ offset, int* __restrict__ sorted_src) {
  __shared__ int sp[SB];
  __shared__ int s[SB];
  const int tid = threadIdx.x;
  int pv = (tid < NSB) ? partial[tid] : 0;
  sp[tid] = pv;
  __syncthreads();
  for (int off = 1; off < SB; off <<= 1) {
    int t = (tid >= off) ? sp[tid - off] : 0;
    __syncthreads();
    sp[tid] += t;
    __syncthreads();
  }
  int base = (blockIdx.x == 0) ? 0 : sp[blockIdx.x - 1];

  int idx = blockIdx.x * SB + tid;
  int dgv = (idx < N_NODES) ? deg[idx] : 0;
  int dg4 = (dgv + 3) & ~3;
  s[tid] = dg4;
  __syncthreads();
  for (int off = 1; off < SB; off <<= 1) {
    int t = (tid >= off) ? s[tid - off] : 0;
    __syncthreads();
    s[tid] += t;
    __syncthreads();
  }
  if (idx < N_NODES) {
    int o = base + s[tid] - dg4;  // exclusive
    offset[idx] = o;
    for (int t2 = dgv; t2 < dg4; ++t2) sorted_src[o + t2] = N_NODES;
  }
}

// ---------------------------------------------------------------------------
// scatter edge sources into dst-grouped (padded) order
// ---------------------------------------------------------------------------
__global__ __launch_bounds__(256) void fill_kernel(
    const int* __restrict__ ei, const int* __restrict__ offset,
    int* __restrict__ cursor, int* __restrict__ sorted_src) {
  int e = blockIdx.x * blockDim.x + threadIdx.x;
  if (e >= N_EDGES) return;
  int d = ei[N_EDGES + e];
  int p = offset[d] + atomicAdd(&cursor[d], 1);
  sorted_src[p] = ei[e];
}

// ---------------------------------------------------------------------------
// Barrier-free fused gather-mean + MFMA transform + ReLU + BN partials.
// 512 threads = 8 waves; each wave owns ONE 16-node tile end-to-end:
//   gather: groups of 16 lanes each read one neighbor row as uint2
//           (4 rows per VMEM instr), fp32-accumulate, xor-shuffle reduce,
//           write bf16 mean rows into a private LDS slab (36-dword stride).
//   mfma:   4 col-tiles x (2 mean + 2 x) 16x16x32 MFMAs; B-frags from the
//           block-shared prepacked LDS; ReLU + store + BN partial sums.
// No __syncthreads in the hot path (only prepack + final BN merge).
// ---------------------------------------------------------------------------
__global__ __launch_bounds__(512) void gather_mfma_kernel(
    const uint* __restrict__ xb,        // [N+1][32] packed bf16 pairs
    const int* __restrict__ sorted_src,
    const int* __restrict__ offset,
    const int* __restrict__ deg,
    const float* __restrict__ Wl,
    const float* __restrict__ bl,
    const float* __restrict__ Wr,
    float* __restrict__ hout,           // = d_out, pre-BN h
    float* __restrict__ sums) {         // [0:64) sum, [64:128) sumsq
  __shared__ short8 bfrag[2][4][2][64];            // 16 KB, block-shared
  __shared__ __align__(16) uint smean[8][16 * 36]; // 18 KB, per-wave slabs
  __shared__ float bsum[D], bsq[D];

  const int tid = threadIdx.x;
  const int lane = tid & 63;
  const int w = tid >> 6;

  // Prepack weight B-fragments: B[k][col] = W[col][k]; lane l holds
  // k = kk*32 + (l>>4)*8 + i, col = ct*16 + (l&15).
  for (int e = tid; e < 1024; e += SB) {
    int mat = e >> 9, r = e & 511;
    int ct = r >> 7, kk = (r >> 6) & 1, l = r & 63;
    int col = ct * 16 + (l & 15);
    int k0 = kk * 32 + (l >> 4) * 8;
    const float* W = mat ? Wr : Wl;
    short8 sv;
#pragma unroll
    for (int i = 0; i < 8; ++i) sv[i] = (short)f2bf(W[col * 64 + k0 + i]);
    bfrag[mat][ct][kk][l] = sv;
  }
  if (tid < D) { bsum[tid] = 0.f; bsq[tid] = 0.f; }
  __syncthreads();

  float psum[4] = {0.f, 0.f, 0.f, 0.f};
  float psq[4] = {0.f, 0.f, 0.f, 0.f};

  const int t = blockIdx.x * 8 + w;  // tile id, one per wave
  if (t < TILES) {
    const int n0 = t * 16;
    const int q2 = lane & 15;  // uint2 index within a row
    const int g = lane >> 4;   // neighbor-row group 0..3

    // ---- gather 16 node means into this wave's LDS slab ----
    for (int s = 0; s < 16; ++s) {
      const int n = n0 + s;
      const int dgv = __builtin_amdgcn_readfirstlane(deg[n]);
      const int off = __builtin_amdgcn_readfirstlane(offset[n]);
      const int dg4 = (dgv + 3) & ~3;
      float a0 = 0.f, a1 = 0.f, a2 = 0.f, a3 = 0.f;
      for (int base = 0; base < dg4; base += 64) {
        int rem = dg4 - base;
        int m = rem < 64 ? rem : 64;  // multiple of 4
        int ids = sorted_src[off + base + lane];
        for (int j = 0; j < m; j += 4) {
          int i0 = __builtin_amdgcn_readlane(ids, j);
          int i1 = __builtin_amdgcn_readlane(ids, j + 1);
          int i2 = __builtin_amdgcn_readlane(ids, j + 2);
          int i3 = __builtin_amdgcn_readlane(ids, j + 3);
          int s01 = (g & 1) ? i1 : i0;
          int s23 = (g & 1) ? i3 : i2;
          int sel = (g & 2) ? s23 : s01;
          uint2 r = *(const uint2*)&xb[(size_t)sel * 32 + q2 * 2];
          a0 += __uint_as_float(r.x << 16);
          a1 += __uint_as_float(r.x & 0xffff0000u);
          a2 += __uint_as_float(r.y << 16);
          a3 += __uint_as_float(r.y & 0xffff0000u);
        }
      }
      a0 += __shfl_xor(a0, 16, 64); a0 += __shfl_xor(a0, 32, 64);
      a1 += __shfl_xor(a1, 16, 64); a1 += __shfl_xor(a1, 32, 64);
      a2 += __shfl_xor(a2, 16, 64); a2 += __shfl_xor(a2, 32, 64);
      a3 += __shfl_xor(a3, 16, 64); a3 += __shfl_xor(a3, 32, 64);
      if (lane < 16) {
        float inv = 1.0f / fmaxf((float)dgv, 1.0f);
        uint2 p;
        p.x = ((uint)f2bf(a1 * inv) << 16) | (uint)f2bf(a0 * inv);
        p.y = ((uint)f2bf(a3 * inv) << 16) | (uint)f2bf(a2 * inv);
        *(uint2*)&smean[w][s * 36 + q2 * 2] = p;
      }
    }

    // ---- MFMA transform: rows n0..n0+15, all 64 output cols ----
    const int r16 = lane & 15;
    const int kg = lane >> 4;
    short8 am0 = *(const short8*)&smean[w][r16 * 36 + kg * 4];
    short8 am1 = *(const short8*)&smean[w][r16 * 36 + 16 + kg * 4];
    const short8* xbf = (const short8*)xb;  // 16B units, 8 per row
    short8 ax0 = xbf[(size_t)(n0 + r16) * 8 + kg];
    short8 ax1 = xbf[(size_t)(n0 + r16) * 8 + 4 + kg];
    float biasv[4];
#pragma unroll
    for (int ct = 0; ct < 4; ++ct) biasv[ct] = bl[ct * 16 + r16];

#pragma unroll
    for (int ct = 0; ct < 4; ++ct) {
      f32x4 acc = {0.f, 0.f, 0.f, 0.f};
      acc = __builtin_amdgcn_mfma_f32_16x16x32_bf16(am0, bfrag[0][ct][0][lane], acc, 0, 0, 0);
      acc = __builtin_amdgcn_mfma_f32_16x16x32_bf16(am1, bfrag[0][ct][1][lane], acc, 0, 0, 0);
      acc = __builtin_amdgcn_mfma_f32_16x16x32_bf16(ax0, bfrag[1][ct][0][lane], acc, 0, 0, 0);
      acc = __builtin_amdgcn_mfma_f32_16x16x32_bf16(ax1, bfrag[1][ct][1][lane], acc, 0, 0, 0);
#pragma unroll
      for (int r = 0; r < 4; ++r) {
        float hv = fmaxf(acc[r] + biasv[ct], 0.f);
        hout[(size_t)(n0 + kg * 4 + r) * D + ct * 16 + r16] = hv;
        psum[ct] += hv;
        psq[ct] += hv * hv;
      }
    }
  }

  // ---- BN partial merge (all waves, uniform path) ----
#pragma unroll
  for (int ct = 0; ct < 4; ++ct) {
    float v1 = psum[ct], v2 = psq[ct];
    v1 += __shfl_xor(v1, 16, 64); v1 += __shfl_xor(v1, 32, 64);
    v2 += __shfl_xor(v2, 16, 64); v2 += __shfl_xor(v2, 32, 64);
    if (lane < 16) {
      atomicAdd(&bsum[ct * 16 + lane], v1);
      atomicAdd(&bsq[ct * 16 + lane], v2);
    }
  }
  __syncthreads();
  if (tid < D) {
    atomicAdd(&sums[tid], bsum[tid]);
    atomicAdd(&sums[D + tid], bsq[tid]);
  }
}

// ---------------------------------------------------------------------------
// finalize (BN stats folded in): out = x + h*scale + shift, in place in d_out.
// ---------------------------------------------------------------------------
__global__ __launch_bounds__(256) void finalize_kernel(
    const float* __restrict__ x,
    const float* __restrict__ sums,
    const float* __restrict__ gamma,
    const float* __restrict__ beta,
    float* __restrict__ out) {
  __shared__ float ssc[D], ssh[D];
  const int tid = threadIdx.x;
  if (tid < D) {
    float mu = sums[tid] / (float)N_NODES;
    float var = sums[D + tid] / (float)N_NODES - mu * mu;
    float inv = rsqrtf(fmaxf(var, 0.f) + BN_EPS);
    float sc = gamma[tid] * inv;
    ssc[tid] = sc;
    ssh[tid] = beta[tid] - mu * sc;
  }
  __syncthreads();
  const int total = N_NODES * D / 4;
  int i = blockIdx.x * 256 + tid;
  if (i >= total) return;
  int qq = i & 15;
  float4 sc = *(const float4*)&ssc[qq * 4];
  float4 sh = *(const float4*)&ssh[qq * 4];
  float4 hv = ((const float4*)out)[i];
  float4 xv = ((const float4*)x)[i];
  float4 r;
  r.x = xv.x + hv.x * sc.x + sh.x;
  r.y = xv.y + hv.y * sc.y + sh.y;
  r.z = xv.z + hv.z * sc.z + sh.z;
  r.w = xv.w + hv.w * sc.w + sh.w;
  ((float4*)out)[i] = r;
}

extern "C" void kernel_launch(void* const* d_in, const int* in_sizes, int n_in,
                              void* d_out, int out_size, void* d_ws, size_t ws_size,
                              hipStream_t stream) {
  const float* x     = (const float*)d_in[0];
  const int*   ei    = (const int*)d_in[1];
  const float* Wl    = (const float*)d_in[2];
  const float* bl    = (const float*)d_in[3];
  const float* Wr    = (const float*)d_in[4];
  const float* gamma = (const float*)d_in[5];
  const float* beta  = (const float*)d_in[6];
  float* out = (float*)d_out;

  // workspace layout (4B units); zeroed region first
  int* deg        = (int*)d_ws;                    // N   (zeroed)
  int* cursor     = deg + N_NODES;                 // N   (zeroed)
  float* sums     = (float*)(cursor + N_NODES);    // 128 (zeroed)
  int* sorted_src = (int*)(sums + 2 * D);          // E + 3N + 64 (padded CSR)
  int* offset     = sorted_src + (N_EDGES + 3 * N_NODES + 64);  // N
  int* partial    = offset + N_NODES;              // NSB
  size_t xb_off   = (size_t)(partial + NSB - (int*)d_ws);
  xb_off = (xb_off + 3) & ~(size_t)3;              // 16B align
  uint* xb        = (uint*)d_ws + xb_off;          // (N+1)*32 bf16-pair rows

  size_t zero_bytes = (size_t)(2 * N_NODES + 2 * D) * sizeof(int);
  hipMemsetAsync(d_ws, 0, zero_bytes, stream);

  const int eblocks = (N_EDGES + 255) / 256;
  convert_degree_kernel<<<eblocks, 256, 0, stream>>>(x, ei, deg, (uint4*)xb);
  scan1_kernel<<<NSB, SB, 0, stream>>>(deg, partial);
  scan2_kernel<<<NSB, SB, 0, stream>>>(deg, partial, offset, sorted_src);
  fill_kernel<<<eblocks, 256, 0, stream>>>(ei, offset, cursor, sorted_src);
  gather_mfma_kernel<<<GT_BLOCKS, SB, 0, stream>>>(
      xb, sorted_src, offset, deg, Wl, bl, Wr, out, sums);
  finalize_kernel<<<(N_NODES * D / 4 + 255) / 256, 256, 0, stream>>>(
      x, sums, gamma, beta, out);
}